// Round 15
// baseline (568.052 us; speedup 1.0000x reference)
//
#include <hip/hip_runtime.h>
#include <hip/hip_bf16.h>

// x: [B=1024, N=65536] f32, index: [N] i32 permutation, group size 64.
#define BATCH   1024
#define NEUR    65536
#define NGRP    1024
#define NCHUNK  8
#define CHUNK   (NEUR / NCHUNK)       // 8192 floats per chunk (32 KB LDS)
#define CHUNK_F4 (CHUNK / 4)          // 2048 float4
#define BLKT    512                   // fused-kernel block size
#define F4T1    (CHUNK_F4 / BLKT)     // 4 float4 per thread (staging)
#define KMAX    16                    // padded slots per (chunk, group) cell
#define SENT    CHUNK                 // sentinel LDS slot holding 0.0f
#define BLK     1024                  // build_tables block
#define ROW_F4  (NEUR / 4)            // 16384
#define HALF_F4 (ROW_F4 / 2)          // 8192
#define CONS_ITERS (HALF_F4 / BLKT)   // 16
#define BUCKET_ELEMS (NCHUNK * NGRP * KMAX)   // 131072 u16 = 256 KB
#define SPILL_CAP 1024
#define NPROD   512                   // producer blocks (low bids: scheduled first)
#define NCONS   512                   // consumer blocks
#define A_ITEMS (BATCH * NCHUNK)      // 8192 -> exactly 16 per producer
#define B_ITEMS (BATCH * 2)           // 2048 -> exactly 4 per consumer

typedef float          f32x4 __attribute__((ext_vector_type(4)));
typedef unsigned short u16x8 __attribute__((ext_vector_type(8)));
typedef unsigned short u16x4 __attribute__((ext_vector_type(4)));

// ws: [gof u16 128 KB][bucket 256 KB][part 32 MB][cnt 4 KB][spill 4 KB]
// (cnt and spill[0] contiguous -> one memsetAsync re-zeroes both per call)

// Wave == one group. Ballot/popcount slots each member into its source-chunk
// cell (transposed [cell][slot]); wave also writes its own pad sentinels.
// Overflow (~25 chip-wide) -> spill list, handled by producers from LDS.
__global__ void build_tables(const int* __restrict__ index,
                             unsigned short* __restrict__ gof,
                             unsigned short* __restrict__ bucket,
                             unsigned int* __restrict__ spill) {
    const int p    = blockIdx.x * blockDim.x + threadIdx.x;
    const int lane = threadIdx.x & 63;
    const int g    = p >> 6;
    const int s    = index[p];
    gof[s] = (unsigned short)g;
    const int c = s >> 13;                                 // s / CHUNK
    unsigned long long mc = 0;
    int count[NCHUNK];
    #pragma unroll
    for (int cc = 0; cc < NCHUNK; ++cc) {
        unsigned long long m = __ballot(c == cc);
        if (cc == c) mc = m;
        count[cc] = __popcll(m);
    }
    const int k = __popcll(mc & ((1ull << lane) - 1ull));
    if (k < KMAX) {
        bucket[((size_t)(c * NGRP + g)) * KMAX + k] = (unsigned short)(s & (CHUNK - 1));
    } else {
        unsigned int pos = atomicAdd(spill, 1u);
        if (pos < SPILL_CAP - 1)
            spill[1 + pos] = ((unsigned)g << 16) | (unsigned)s;  // s carries chunk
    }
    #pragma unroll
    for (int j = 0; j < 2; ++j) {
        const int slot = lane + j * 64;                    // 0..127
        const int cc = slot >> 4, kk = slot & 15;
        if (kk >= count[cc])
            bucket[((size_t)(cc * NGRP + g)) * KMAX + kk] = (unsigned short)SENT;
    }
}

// Fused producer/consumer (R15): overlaps k1's HBM read stream with k3's HBM
// write stream. Producers (bids 0..511) run R14's k1 body 16x; consumers
// (bids 512..1023) spin on cnt[row]==8 (R9-validated agent-scope pattern)
// then run R14's k3 body 4x. All 1024 blocks resident (32.8 KB LDS, <=64
// VGPR -> 4/CU); producers never wait -> deadlock-free, graceful fallback.
__global__ __launch_bounds__(BLKT, 8)
void fused(const float* __restrict__ x,
           const unsigned short* __restrict__ gof,
           const unsigned short* __restrict__ bucket,
           const unsigned int* __restrict__ spill,
           float* __restrict__ part,
           unsigned int* __restrict__ cnt,
           float* __restrict__ out) {
    __shared__ float xs[CHUNK + 16];   // producer: chunk+sentinel; consumer: rsum
    const int bid = blockIdx.x;
    const int t   = threadIdx.x;

    if (bid < NPROD) {
        // ------------------------------ producer ------------------------------
        const unsigned int ns = spill[0];
        if (t == 0) xs[SENT] = 0.0f;
        int pending_b = -1;

        for (int i = 0; i < A_ITEMS / NPROD; ++i) {
            const int a = bid + i * NPROD;
            const int b = a >> 3, c = a & 7;

            // Hoisted independent L2 loads: in flight during staging.
            const unsigned short* __restrict__ bk0 =
                bucket + ((size_t)(c * NGRP + t)) * KMAX;
            const unsigned short* __restrict__ bk1 =
                bucket + ((size_t)(c * NGRP + t + 512)) * KMAX;
            const u16x8 w0 = *(const u16x8*)(bk0);
            const u16x8 w1 = *(const u16x8*)(bk0 + 8);
            const u16x8 w2 = *(const u16x8*)(bk1);
            const u16x8 w3 = *(const u16x8*)(bk1 + 8);

            __syncthreads();           // WAR on xs + prev part stores retired
            if (t == 0 && pending_b >= 0)
                __hip_atomic_fetch_add(&cnt[pending_b], 1u, __ATOMIC_RELEASE,
                                       __HIP_MEMORY_SCOPE_AGENT);

            const float4* __restrict__ src =
                (const float4*)(x + (size_t)b * NEUR + (size_t)c * CHUNK);
            float4* xs4 = (float4*)xs;
            #pragma unroll
            for (int j = 0; j < F4T1; ++j) {
                __builtin_amdgcn_global_load_lds(
                    (const __attribute__((address_space(1))) unsigned int*)(src + j * BLKT + t),
                    (__attribute__((address_space(3))) unsigned int*)(xs4 + j * BLKT + t),
                    16, 0, 0);
            }
            __syncthreads();           // staging DMA complete

            float a0 = 0.0f, a1 = 0.0f, b0 = 0.0f, b1 = 0.0f;
            #pragma unroll
            for (int j = 0; j < 8; ++j) {
                a0 += xs[w0[j]];
                a1 += xs[w1[j]];
                b0 += xs[w2[j]];
                b1 += xs[w3[j]];       // pads hit the 0.0 sentinel
            }
            for (unsigned int e = 0; e < ns; ++e) {
                const unsigned int ent = spill[1 + e];
                if (((ent >> 13) & 7u) == (unsigned)c) {
                    const float v = xs[ent & 0x1FFFu];
                    const int gg = (int)(ent >> 16);
                    if (gg == t)            a1 += v;
                    else if (gg == t + 512) b1 += v;
                }
            }
            float* __restrict__ prow = part + ((size_t)b * NCHUNK + c) * NGRP;
            prow[t]       = a0 + a1;
            prow[t + 512] = b0 + b1;
            pending_b = b;
        }
        __syncthreads();               // final item's stores retired
        if (t == 0 && pending_b >= 0)
            __hip_atomic_fetch_add(&cnt[pending_b], 1u, __ATOMIC_RELEASE,
                                   __HIP_MEMORY_SCOPE_AGENT);
    } else {
        // ------------------------------ consumer ------------------------------
        float* rsum = xs;              // alias LDS (4 KB used)
        const int q = bid - NPROD;

        for (int i = 0; i < B_ITEMS / NCONS; ++i) {
            const int w = q + i * NCONS;
            const int b = w >> 1, half = w & 1;

            if (t == 0) {
                while (__hip_atomic_load(&cnt[b], __ATOMIC_ACQUIRE,
                                         __HIP_MEMORY_SCOPE_AGENT) != NCHUNK)
                    __builtin_amdgcn_s_sleep(8);
            }
            __syncthreads();           // row ready; also WAR on rsum

            float s0 = 0.0f, s1 = 0.0f;
            #pragma unroll
            for (int c = 0; c < NCHUNK; ++c) {   // R9-proven agent atomic loads
                const float* __restrict__ prow = part + ((size_t)b * NCHUNK + c) * NGRP;
                s0 += __hip_atomic_load(prow + t,       __ATOMIC_RELAXED,
                                        __HIP_MEMORY_SCOPE_AGENT);
                s1 += __hip_atomic_load(prow + t + 512, __ATOMIC_RELAXED,
                                        __HIP_MEMORY_SCOPE_AGENT);
            }
            rsum[t]       = 1.0f / s0;
            rsum[t + 512] = 1.0f / s1;
            __syncthreads();

            const float4* __restrict__ xrow4 = (const float4*)(x + (size_t)b * NEUR);
            const u16x4*  __restrict__ gof4  = (const u16x4*)gof;
            f32x4*        __restrict__ orow4 = (f32x4*)(out + (size_t)b * NEUR);

            #pragma unroll
            for (int it = 0; it < CONS_ITERS; ++it) {
                const int e = half * HALF_F4 + it * BLKT + t;
                const float4 v = xrow4[e];     // L3-hot (staged moments ago)
                const u16x4 g = gof4[e];       // 128 KB table, L2-resident
                f32x4 o;
                o.x = v.x * rsum[g.x];
                o.y = v.y * rsum[g.y];
                o.z = v.z * rsum[g.z];
                o.w = v.w * rsum[g.w];
                __builtin_nontemporal_store(o, &orow4[e]);  // don't evict x
            }
        }
    }
}

extern "C" void kernel_launch(void* const* d_in, const int* in_sizes, int n_in,
                              void* d_out, int out_size, void* d_ws, size_t ws_size,
                              hipStream_t stream) {
    const float* x     = (const float*)d_in[0];
    const int*   index = (const int*)d_in[1];
    float*       out   = (float*)d_out;

    unsigned short* gof    = (unsigned short*)d_ws;                 // 128 KB
    unsigned short* bucket = gof + NEUR;                            // 256 KB
    float*          part   = (float*)(bucket + BUCKET_ELEMS);       // 32 MB
    unsigned int*   cnt    = (unsigned int*)(part + (size_t)BATCH * NCHUNK * NGRP);
    unsigned int*   spill  = cnt + BATCH;                           // 4 KB

    // One memset re-zeroes cnt[1024] AND spill[0] (contiguous) every call.
    hipMemsetAsync(cnt, 0, (BATCH + 1) * sizeof(unsigned int), stream);
    build_tables<<<NEUR / BLK, BLK, 0, stream>>>(index, gof, bucket, spill);
    fused<<<NPROD + NCONS, BLKT, 0, stream>>>(x, gof, bucket, spill,
                                              part, cnt, out);
}

// Round 16
// 154.058 us; speedup vs baseline: 3.6873x; 3.6873x over previous
//
#include <hip/hip_runtime.h>
#include <hip/hip_bf16.h>

// x: [B=1024, N=65536] f32, index: [N] i32 permutation, group size 64.
#define BATCH   1024
#define NEUR    65536
#define NGRP    1024
#define NCHUNK  8
#define CHUNK   (NEUR / NCHUNK)       // 8192 floats per chunk (32 KB LDS)
#define CHUNK_F4 (CHUNK / 4)          // 2048 float4
#define BLK1    512                   // k1 block: 4 blocks/CU (R13-proven)
#define F4T1    (CHUNK_F4 / BLK1)     // 4 float4 per thread
#define KMAX    16                    // padded slots per (chunk, group) cell
#define SENT    CHUNK                 // sentinel LDS slot holding 0.0f
#define BLK     1024                  // build/k3 block
#define ROW_F4  (NEUR / 4)            // 16384
#define HALF_F4 (ROW_F4 / 2)          // 8192
#define H_ITERS (HALF_F4 / BLK)       // 8
#define BUCKET_ELEMS (NCHUNK * NGRP * KMAX)   // 131072 u16 = 256 KB
#define SPILL_CAP 1024
#define TILE    512                   // rows per k1/k3 pair (R16: L3 tiling —
                                      // 128 MB staged per tile << 256 MB L3)

typedef float          f32x4 __attribute__((ext_vector_type(4)));
typedef unsigned short u16x8 __attribute__((ext_vector_type(8)));
typedef unsigned short u16x4 __attribute__((ext_vector_type(4)));

// ws: [gof u16 128 KB][bucket 256 KB][part 32 MB][spill 4 KB]

// Wave == one group (64 consecutive permuted positions). Ballot/popcount
// slots each member into its source-chunk cell (transposed [cell][slot]);
// the wave also writes its own cells' pad sentinels. Overflow (~25 entries
// chip-wide) -> spill list, handled in k1 from LDS.
__global__ void build_tables(const int* __restrict__ index,
                             unsigned short* __restrict__ gof,
                             unsigned short* __restrict__ bucket,
                             unsigned int* __restrict__ spill) {
    const int p    = blockIdx.x * blockDim.x + threadIdx.x;
    const int lane = threadIdx.x & 63;
    const int g    = p >> 6;
    const int s    = index[p];
    gof[s] = (unsigned short)g;
    const int c = s >> 13;                                 // s / CHUNK
    unsigned long long mc = 0;
    int count[NCHUNK];
    #pragma unroll
    for (int cc = 0; cc < NCHUNK; ++cc) {
        unsigned long long m = __ballot(c == cc);
        if (cc == c) mc = m;
        count[cc] = __popcll(m);
    }
    const int k = __popcll(mc & ((1ull << lane) - 1ull));
    if (k < KMAX) {
        bucket[((size_t)(c * NGRP + g)) * KMAX + k] = (unsigned short)(s & (CHUNK - 1));
    } else {
        unsigned int pos = atomicAdd(spill, 1u);
        if (pos < SPILL_CAP - 1)
            spill[1 + pos] = ((unsigned)g << 16) | (unsigned)s;  // s carries chunk
    }
    // Pad slots kk in [count_c, KMAX): 8 cells x 16 slots = 128 = 2 lane-passes.
    #pragma unroll
    for (int j = 0; j < 2; ++j) {
        const int slot = lane + j * 64;                    // 0..127
        const int cc = slot >> 4, kk = slot & 15;
        if (kk >= count[cc])
            bucket[((size_t)(cc * NGRP + g)) * KMAX + kk] = (unsigned short)SENT;
    }
}

// k1: one block per (row, chunk) within the tile. R14-proven body: staging
// via global_load_lds width=16, bucket u16x8 loads + spill count hoisted
// above the barrier, 16 branch-free sentinel-padded gather-adds per group.
__global__ __launch_bounds__(BLK1, 8)
void k1_partial(const float* __restrict__ x,
                const unsigned short* __restrict__ bucket,
                const unsigned int* __restrict__ spill,
                float* __restrict__ part,
                int row_base) {
    __shared__ float xs[CHUNK + 16];   // 32 KB chunk + sentinel
    const int bc = blockIdx.x;
    const int b  = row_base + (bc >> 3);   // row
    const int c  = bc & 7;                 // chunk
    const int t  = threadIdx.x;

    // Hoisted independent L2 loads: in flight during staging.
    const unsigned short* __restrict__ bk0 =
        bucket + ((size_t)(c * NGRP + t)) * KMAX;          // 32 B contiguous
    const unsigned short* __restrict__ bk1 =
        bucket + ((size_t)(c * NGRP + t + 512)) * KMAX;
    const u16x8 w0 = *(const u16x8*)(bk0);
    const u16x8 w1 = *(const u16x8*)(bk0 + 8);
    const u16x8 w2 = *(const u16x8*)(bk1);
    const u16x8 w3 = *(const u16x8*)(bk1 + 8);
    const unsigned int ns = spill[0];

    if (t == 0) xs[SENT] = 0.0f;

    // Async global->LDS staging, width=16 (wave-uniform base + lane*16).
    const float4* __restrict__ src =
        (const float4*)(x + (size_t)b * NEUR + (size_t)c * CHUNK);
    float4* xs4 = (float4*)xs;
    #pragma unroll
    for (int i = 0; i < F4T1; ++i) {
        __builtin_amdgcn_global_load_lds(
            (const __attribute__((address_space(1))) unsigned int*)(src + i * BLK1 + t),
            (__attribute__((address_space(3))) unsigned int*)(xs4 + i * BLK1 + t),
            16, 0, 0);
    }
    __syncthreads();                   // drains vmcnt (DMA) + lgkmcnt (sentinel)

    float a0 = 0.0f, a1 = 0.0f, b0 = 0.0f, b1 = 0.0f;
    #pragma unroll
    for (int j = 0; j < 8; ++j) {
        a0 += xs[w0[j]];
        a1 += xs[w1[j]];
        b0 += xs[w2[j]];
        b1 += xs[w3[j]];               // pads hit the 0.0 sentinel
    }

    // Spill entries for THIS chunk: add from LDS (~25 chip-wide, wave scan).
    for (unsigned int e = 0; e < ns; ++e) {
        const unsigned int ent = spill[1 + e];
        if (((ent >> 13) & 7u) == (unsigned)c) {
            const float v = xs[ent & 0x1FFFu];
            const int gg = (int)(ent >> 16);
            if (gg == t)            a1 += v;
            else if (gg == t + 512) b1 += v;
        }
    }

    float* __restrict__ prow = part + ((size_t)b * NCHUNK + c) * NGRP;
    prow[t]       = a0 + a1;           // coalesced
    prow[t + 512] = b0 + b1;
}

// k3: one block per HALF-row within the tile, reverse order (hottest rows
// first). 8 coalesced partial reads, reciprocal, then coalesced scale +
// nontemporal store. The tile's x was staged by k1 moments ago -> L3-hot
// (R16: in the untiled version, early rows were evicted — 256 MB of x
// streaming through a 256 MB L3 — measured as k3 ~2.9 TB/s eff. write).
__global__ __launch_bounds__(BLK, 8)
void k3_scale(const float* __restrict__ x,
              const unsigned short* __restrict__ gof,
              const float* __restrict__ part,
              float* __restrict__ out,
              int row_base) {
    __shared__ float rsum[NGRP];       // 4 KB only
    const int rb   = blockIdx.x;
    const int b    = row_base + (TILE - 1) - (rb >> 1);
    const int half = rb & 1;
    const int t    = threadIdx.x;

    const float* __restrict__ prow = part + (size_t)b * NCHUNK * NGRP;
    float s = 0.0f;
    #pragma unroll
    for (int c = 0; c < NCHUNK; ++c) s += prow[c * NGRP + t];  // 8 indep loads
    rsum[t] = 1.0f / s;
    __syncthreads();

    const float4* __restrict__ xrow4 = (const float4*)(x + (size_t)b * NEUR);
    const u16x4*  __restrict__ gof4  = (const u16x4*)gof;  // 8 B per float4
    f32x4*        __restrict__ orow4 = (f32x4*)(out + (size_t)b * NEUR);

    #pragma unroll
    for (int it = 0; it < H_ITERS; ++it) {
        const int e = half * HALF_F4 + it * BLK + t;
        const float4 v = xrow4[e];     // L3-hot re-read (tiled)
        const u16x4 g = gof4[e];       // 128 KB table, L2-resident
        f32x4 o;
        o.x = v.x * rsum[g.x];
        o.y = v.y * rsum[g.y];
        o.z = v.z * rsum[g.z];
        o.w = v.w * rsum[g.w];
        __builtin_nontemporal_store(o, &orow4[e]);  // don't evict x from L3
    }
}

extern "C" void kernel_launch(void* const* d_in, const int* in_sizes, int n_in,
                              void* d_out, int out_size, void* d_ws, size_t ws_size,
                              hipStream_t stream) {
    const float* x     = (const float*)d_in[0];
    const int*   index = (const int*)d_in[1];
    float*       out   = (float*)d_out;

    unsigned short* gof    = (unsigned short*)d_ws;                 // 128 KB
    unsigned short* bucket = gof + NEUR;                            // 256 KB
    float*          part   = (float*)(bucket + BUCKET_ELEMS);       // 32 MB
    unsigned int*   spill  = (unsigned int*)(part + (size_t)BATCH * NCHUNK * NGRP);

    hipMemsetAsync(spill, 0, sizeof(unsigned int), stream);  // zero spill count
    build_tables<<<NEUR / BLK, BLK, 0, stream>>>(index, gof, bucket, spill);
    // R16: tile k1->k3 pairs over row halves so each k3 re-reads only the
    // 128 MB its k1 just staged (L3-resident), instead of a cold full pass.
    for (int rb = 0; rb < BATCH; rb += TILE) {
        k1_partial<<<TILE * NCHUNK, BLK1, 0, stream>>>(x, bucket, spill, part, rb);
        k3_scale<<<TILE * 2, BLK, 0, stream>>>(x, gof, part, out, rb);
    }
}